// Round 1
// baseline (601.200 us; speedup 1.0000x reference)
//
#include <hip/hip_runtime.h>
#include <cstdint>
#include <cstddef>

// ---------------------------------------------------------------------------
// QuantumRLAgent: 18-qubit statevector sim + MLPs.
// Structure: the batch collapses into ONE statevector (xc is flattened and
// added to sv). Dominant cost: two 524288x64 fp32 matvecs (268 MB weight
// stream) -> HBM-bound ~43us floor. Circuit: fused 1q gates (RZ*RY*RX) per
// qubit; CNOT chain == index permutation P(i) = (i ^ (i<<1)) & 0x3FFFF,
// fused into the next sweep's gather. Layer-1 state is a product state
// (analytic), so only layers 2,3 need sweeps.
// ---------------------------------------------------------------------------

#define NQb   18
#define DIMSZ 262144      // 2^18
#define PMASK 0x3FFFF
#define XLEN  73728       // 4096*18

typedef float2 cplx;

__device__ __forceinline__ cplx cmul(cplx a, cplx b) {
  return make_float2(a.x*b.x - a.y*b.y, a.x*b.y + a.y*b.x);
}
__device__ __forceinline__ cplx cadd(cplx a, cplx b) {
  return make_float2(a.x + b.x, a.y + b.y);
}

// --------------------------------------------------------------------------
// K_prep: fused U = Rz*Ry*Rx per (layer,qubit); layer-0 product tables;
// zero the accumulators (dots[128], xn2, L2).
// --------------------------------------------------------------------------
__global__ void k_prep(const float* __restrict__ qp, cplx* __restrict__ Ug,
                       cplx* __restrict__ prodLow, cplx* __restrict__ prodHigh,
                       float* __restrict__ accs) {
  __shared__ cplx Ush[54][4];
  int t = threadIdx.x;
  if (t < 132) accs[t] = 0.0f;
  if (t < 54) {
    float a = qp[t*3+0], b = qp[t*3+1], c = qp[t*3+2];
    float ca = cosf(0.5f*a), sa = sinf(0.5f*a);
    float cb = cosf(0.5f*b), sb = sinf(0.5f*b);
    float cc = cosf(0.5f*c), sc = sinf(0.5f*c);
    // M = Ry*Rx
    cplx m00 = make_float2( cb*ca,  sb*sa);
    cplx m01 = make_float2(-sb*ca, -cb*sa);
    cplx m10 = make_float2( sb*ca, -cb*sa);
    cplx m11 = make_float2( cb*ca, -sb*sa);
    // U = Rz*M : row0 *= e^{-ic/2}, row1 *= e^{+ic/2}
    cplx e0 = make_float2(cc, -sc), e1 = make_float2(cc, sc);
    cplx u00 = cmul(e0, m00), u01 = cmul(e0, m01);
    cplx u10 = cmul(e1, m10), u11 = cmul(e1, m11);
    Ush[t][0] = u00; Ush[t][1] = u01; Ush[t][2] = u10; Ush[t][3] = u11;
    Ug[t*4+0] = u00; Ug[t*4+1] = u01; Ug[t*4+2] = u10; Ug[t*4+3] = u11;
  }
  __syncthreads();
  // layer-0 product state: amp(i) = prod_p U0[17-p][bit_p(i)][0]
  for (int m = t; m < 4096; m += blockDim.x) {
    cplx v = make_float2(1.f, 0.f);
    for (int p = 0; p < 12; ++p) {
      int q = 17 - p;
      cplx f = ((m >> p) & 1) ? Ush[q][2] : Ush[q][0];
      v = cmul(v, f);
    }
    prodLow[m] = v;
  }
  if (t < 64) {
    cplx v = make_float2(1.f, 0.f);
    for (int p = 12; p < 18; ++p) {
      int q = 17 - p;
      cplx f = ((t >> (p - 12)) & 1) ? Ush[q][2] : Ush[q][0];
      v = cmul(v, f);
    }
    prodHigh[t] = v;
  }
}

// --------------------------------------------------------------------------
// K_enc: h = relu(state@w1+b1); enc = h@w2+b2; xc = amp*exp(i*ph).
// 256 blocks x 256 threads, 16 rows/block (4 rows per inner pass).
// Also accumulates xn2 = sum(amp^2) = ||x||^2.
// --------------------------------------------------------------------------
__global__ __launch_bounds__(256) void k_enc(
    const float* __restrict__ state, const float* __restrict__ w1,
    const float* __restrict__ b1, const float* __restrict__ w2,
    const float* __restrict__ b2, float* __restrict__ xRe,
    float* __restrict__ xIm, float* __restrict__ xn2) {
  __shared__ float sState[4][256];
  __shared__ float hS[4][64];
  __shared__ float blockSum;
  int t = threadIdx.x;
  if (t == 0) blockSum = 0.f;
  int j = t & 63, rsub = t >> 6;
  float lsum = 0.f;
  for (int it = 0; it < 4; ++it) {
    int row = blockIdx.x*16 + it*4 + rsub;
    __syncthreads();
    for (int idx = t; idx < 1024; idx += 256)
      sState[idx >> 8][idx & 255] =
          state[(size_t)(blockIdx.x*16 + it*4 + (idx >> 8))*256 + (idx & 255)];
    __syncthreads();
    float acc = b1[j];
    for (int k = 0; k < 256; ++k)
      acc = fmaf(sState[rsub][k], w1[k*64 + j], acc);
    hS[rsub][j] = fmaxf(acc, 0.f);
    __syncthreads();
    if (j < 36) {
      float a = b2[j];
      for (int k = 0; k < 64; ++k) a = fmaf(hS[rsub][k], w2[k*36 + j], a);
      sState[rsub][j] = a;  // stash enc row (sState refilled next pass)
    }
    __syncthreads();
    if (j < 18) {
      float amp = sState[rsub][j], ph = sState[rsub][18 + j];
      float sp, cp;
      sincosf(ph, &sp, &cp);
      int idx = row*18 + j;
      xRe[idx] = amp * cp;
      xIm[idx] = amp * sp;
      lsum += amp * amp;
    }
  }
  atomicAdd(&blockSum, lsum);
  __syncthreads();
  if (t == 0) atomicAdd(xn2, blockSum);
}

// --------------------------------------------------------------------------
// K_sweepA: gates on low 12 bits (qubits 6..17) in a 4096-elem LDS tile.
// mode 0: input = layer-0 product state gathered through perm P.
// mode 1: input = svIn[P(i)] (fuses previous layer's CNOT chain).
// --------------------------------------------------------------------------
__global__ __launch_bounds__(256) void k_sweepA(
    const cplx* __restrict__ Ug, const cplx* __restrict__ prodLow,
    const cplx* __restrict__ prodHigh, const cplx* __restrict__ svIn,
    cplx* __restrict__ svOut, int layer, int mode) {
  __shared__ float sRe[4096], sIm[4096];
  int t = threadIdx.x;
  int base = blockIdx.x << 12;
  for (int e = t; e < 4096; e += 256) {
    int i = base + e;
    int src = (i ^ (i << 1)) & PMASK;   // CNOT-chain permutation
    cplx v;
    if (mode == 0) v = cmul(prodHigh[src >> 12], prodLow[src & 4095]);
    else           v = svIn[src];
    sRe[e] = v.x; sIm[e] = v.y;
  }
  __syncthreads();
  for (int p = 0; p < 12; ++p) {
    int q = 17 - p;
    const cplx* U = Ug + (layer*18 + q)*4;
    cplx u00 = U[0], u01 = U[1], u10 = U[2], u11 = U[3];
    for (int k = t; k < 2048; k += 256) {
      int i0 = ((k >> p) << (p + 1)) | (k & ((1 << p) - 1));
      int i1 = i0 | (1 << p);
      cplx a = make_float2(sRe[i0], sIm[i0]);
      cplx b = make_float2(sRe[i1], sIm[i1]);
      cplx na = cadd(cmul(u00, a), cmul(u01, b));
      cplx nb = cadd(cmul(u10, a), cmul(u11, b));
      sRe[i0] = na.x; sIm[i0] = na.y;
      sRe[i1] = nb.x; sIm[i1] = nb.y;
    }
    __syncthreads();
  }
  for (int e = t; e < 4096; e += 256)
    svOut[base + e] = make_float2(sRe[e], sIm[e]);
}

// --------------------------------------------------------------------------
// K_sweepB: gates on high 6 bits (qubits 0..5). Tile = 64 h-values x 64
// low-indices in LDS; in-place on sv (tiles partition by low index).
// --------------------------------------------------------------------------
__global__ __launch_bounds__(256) void k_sweepB(const cplx* __restrict__ Ug,
                                                cplx* __restrict__ sv,
                                                int layer) {
  __shared__ float tRe[4096], tIm[4096];  // [h*64 + l]
  int t = threadIdx.x;
  int lbase = blockIdx.x << 6;
  for (int m = t; m < 4096; m += 256) {
    int h = m >> 6, l = m & 63;
    cplx v = sv[h*4096 + lbase + l];
    tRe[m] = v.x; tIm[m] = v.y;
  }
  __syncthreads();
  for (int ph = 0; ph < 6; ++ph) {
    int p = 12 + ph, q = 17 - p;
    const cplx* U = Ug + (layer*18 + q)*4;
    cplx u00 = U[0], u01 = U[1], u10 = U[2], u11 = U[3];
    for (int k = t; k < 2048; k += 256) {
      int kh = k >> 6, l = k & 63;
      int h0 = ((kh >> ph) << (ph + 1)) | (kh & ((1 << ph) - 1));
      int h1 = h0 | (1 << ph);
      int i0 = h0*64 + l, i1 = h1*64 + l;
      cplx a = make_float2(tRe[i0], tIm[i0]);
      cplx b = make_float2(tRe[i1], tIm[i1]);
      cplx na = cadd(cmul(u00, a), cmul(u01, b));
      cplx nb = cadd(cmul(u10, a), cmul(u11, b));
      tRe[i0] = na.x; tIm[i0] = na.y;
      tRe[i1] = nb.x; tIm[i1] = nb.y;
    }
    __syncthreads();
  }
  for (int m = t; m < 4096; m += 256) {
    int h = m >> 6, l = m & 63;
    sv[h*4096 + lbase + l] = make_float2(tRe[m], tIm[m]);
  }
}

// --------------------------------------------------------------------------
// K_combine: final perm gather + add normalized x + build cl (re plane then
// im plane, unnormalized) + accumulate L2 = ||sv||^2.
// --------------------------------------------------------------------------
__global__ __launch_bounds__(256) void k_combine(
    const cplx* __restrict__ svIn, const float* __restrict__ xRe,
    const float* __restrict__ xIm, const float* __restrict__ xn2,
    float* __restrict__ cl, float* __restrict__ L2acc) {
  int t = threadIdx.x;
  float xs = xn2[0];
  float invXn = (xs > 0.f) ? (1.0f / sqrtf(xs)) : 1.0f;
  float lsum = 0.f;
  for (int u = 0; u < 4; ++u) {
    int i = blockIdx.x*1024 + u*256 + t;
    int src = (i ^ (i << 1)) & PMASK;
    cplx v = svIn[src];
    if (i < XLEN) {
      v.x = fmaf(xRe[i], invXn, v.x);
      v.y = fmaf(xIm[i], invXn, v.y);
    }
    cl[i] = v.x;
    cl[DIMSZ + i] = v.y;
    lsum += v.x*v.x + v.y*v.y;
  }
  for (int off = 32; off > 0; off >>= 1) lsum += __shfl_down(lsum, off, 64);
  if ((t & 63) == 0) atomicAdd(L2acc, lsum);
}

// --------------------------------------------------------------------------
// K_matvec: dots[mat*64+c] = sum_r cl[r]*W[r,c] / L. HBM-bound 268 MB
// weight stream. 1024 WGs: blockIdx&1 = matrix, blockIdx>>1 = 1024-row chunk.
// Thread t: cols 4*(t&15)..+3, rows (t>>4) + 16*pass. float4 coalesced.
// --------------------------------------------------------------------------
__global__ __launch_bounds__(256) void k_matvec(
    const float* __restrict__ cl, const float* __restrict__ Wdec,
    const float* __restrict__ Wval, const float* __restrict__ L2acc,
    float* __restrict__ dots) {
  __shared__ float clS[1024];
  __shared__ float red[1024];
  int t = threadIdx.x;
  int mat = blockIdx.x & 1;
  size_t r0 = (size_t)(blockIdx.x >> 1) * 1024;
  const float4* cl4 = reinterpret_cast<const float4*>(cl + r0);
  reinterpret_cast<float4*>(clS)[t] = cl4[t];
  __syncthreads();
  const float* W = (mat ? Wval : Wdec) + r0*64 + (size_t)((t & 15)*4);
  int ro = t >> 4;
  float ax = 0.f, ay = 0.f, az = 0.f, aw = 0.f;
#pragma unroll 4
  for (int pass = 0; pass < 64; ++pass) {
    int r = (pass << 4) + ro;
    const float4 w = *reinterpret_cast<const float4*>(W + (size_t)r*64);
    float s = clS[r];
    ax = fmaf(s, w.x, ax);
    ay = fmaf(s, w.y, ay);
    az = fmaf(s, w.z, az);
    aw = fmaf(s, w.w, aw);
  }
  red[t*4+0] = ax; red[t*4+1] = ay; red[t*4+2] = az; red[t*4+3] = aw;
  __syncthreads();
  if (t < 64) {
    int ci0 = t >> 2, jj = t & 3;
    float sum = 0.f;
    for (int r2 = 0; r2 < 16; ++r2) sum += red[(r2*16 + ci0)*4 + jj];
    float invL = 1.0f / sqrtf(L2acc[0]);
    atomicAdd(&dots[mat*64 + t], sum * invL);
  }
}

// --------------------------------------------------------------------------
// K_final: hidden relu + tiny second layers -> 19 outputs.
// --------------------------------------------------------------------------
__global__ void k_final(const float* __restrict__ dots,
                        const float* __restrict__ db1,
                        const float* __restrict__ dw2,
                        const float* __restrict__ db2,
                        const float* __restrict__ vb1,
                        const float* __restrict__ vw2,
                        const float* __restrict__ vb2,
                        float* __restrict__ out) {
  __shared__ float hd[64], hv[64];
  int t = threadIdx.x;
  hd[t] = fmaxf(dots[t] + db1[t], 0.f);
  hv[t] = fmaxf(dots[64 + t] + vb1[t], 0.f);
  __syncthreads();
  if (t < 18) {
    float s = db2[t];
    for (int k = 0; k < 64; ++k) s = fmaf(hd[k], dw2[k*18 + t], s);
    out[t] = s;
  }
  if (t == 20) {
    float s = vb2[0];
    for (int k = 0; k < 64; ++k) s = fmaf(hv[k], vw2[k], s);
    out[18] = s;
  }
}

extern "C" void kernel_launch(void* const* d_in, const int* in_sizes, int n_in,
                              void* d_out, int out_size, void* d_ws,
                              size_t ws_size, hipStream_t stream) {
  const float* state  = (const float*)d_in[0];
  const float* enc_w1 = (const float*)d_in[1];
  const float* enc_b1 = (const float*)d_in[2];
  const float* enc_w2 = (const float*)d_in[3];
  const float* enc_b2 = (const float*)d_in[4];
  const float* qparams= (const float*)d_in[5];
  const float* dec_w1 = (const float*)d_in[6];
  const float* dec_b1 = (const float*)d_in[7];
  const float* dec_w2 = (const float*)d_in[8];
  const float* dec_b2 = (const float*)d_in[9];
  const float* val_w1 = (const float*)d_in[10];
  const float* val_b1 = (const float*)d_in[11];
  const float* val_w2 = (const float*)d_in[12];
  const float* val_b2 = (const float*)d_in[13];

  float* wsf = (float*)d_ws;
  // ws layout (floats): see offsets; total ~1.74M floats (~6.9 MB)
  float* dots     = wsf;                         // 128
  float* xn2      = wsf + 128;                   // 1
  float* L2acc    = wsf + 129;                   // 1
  cplx*  Ug       = (cplx*)(wsf + 256);          // 216 cplx
  cplx*  prodLow  = (cplx*)(wsf + 1024);         // 4096 cplx
  cplx*  prodHigh = (cplx*)(wsf + 9216);         // 64 cplx
  float* xRe      = wsf + 16384;                 // 73728
  float* xIm      = wsf + 90112;                 // 73728
  cplx*  svA      = (cplx*)(wsf + 163840);       // 262144 cplx
  cplx*  svB      = (cplx*)(wsf + 688128);       // 262144 cplx
  float* cl       = wsf + 1212416;               // 524288

  hipLaunchKernelGGL(k_prep, dim3(1), dim3(256), 0, stream,
                     qparams, Ug, prodLow, prodHigh, wsf);
  hipLaunchKernelGGL(k_enc, dim3(256), dim3(256), 0, stream,
                     state, enc_w1, enc_b1, enc_w2, enc_b2, xRe, xIm, xn2);
  // layer 2 gates (layer index 1); input = permuted layer-1 product state
  hipLaunchKernelGGL(k_sweepA, dim3(64), dim3(256), 0, stream,
                     Ug, prodLow, prodHigh, (const cplx*)nullptr, svA, 1, 0);
  hipLaunchKernelGGL(k_sweepB, dim3(64), dim3(256), 0, stream, Ug, svA, 1);
  // layer 3 gates (layer index 2); input = svA gathered through perm P
  hipLaunchKernelGGL(k_sweepA, dim3(64), dim3(256), 0, stream,
                     Ug, prodLow, prodHigh, (const cplx*)svA, svB, 2, 1);
  hipLaunchKernelGGL(k_sweepB, dim3(64), dim3(256), 0, stream, Ug, svB, 2);
  hipLaunchKernelGGL(k_combine, dim3(256), dim3(256), 0, stream,
                     svB, xRe, xIm, xn2, cl, L2acc);
  hipLaunchKernelGGL(k_matvec, dim3(1024), dim3(256), 0, stream,
                     cl, dec_w1, val_w1, L2acc, dots);
  hipLaunchKernelGGL(k_final, dim3(1), dim3(64), 0, stream,
                     dots, dec_b1, dec_w2, dec_b2, val_b1, val_w2, val_b2,
                     (float*)d_out);
}

// Round 2
// 401.219 us; speedup vs baseline: 1.4984x; 1.4984x over previous
//
#include <hip/hip_runtime.h>
#include <cstdint>
#include <cstddef>

// ---------------------------------------------------------------------------
// QuantumRLAgent: 18-qubit statevector sim + MLPs.
// Structure: the batch collapses into ONE statevector (xc is flattened and
// added to sv). Dominant cost: two 524288x64 fp32 matvecs (268 MB weight
// stream) -> HBM-bound ~43us floor. Circuit: fused 1q gates (RZ*RY*RX) per
// qubit; CNOT chain == index permutation P(i) = (i ^ (i<<1)) & 0x3FFFF,
// fused into the next sweep's gather. Layer-1 state is a product state
// (analytic), so only layers 2,3 need sweeps.
//
// R1 -> R2: k_enc was 208us (4 waves/CU, 256-long serial FMA chain on L2
// loads). Rewritten: 1024 blocks, 4 rows/block, 4 independent accumulators.
// Sweeps bumped to 512 threads/block.
// ---------------------------------------------------------------------------

#define NQb   18
#define DIMSZ 262144      // 2^18
#define PMASK 0x3FFFF
#define XLEN  73728       // 4096*18

typedef float2 cplx;

__device__ __forceinline__ cplx cmul(cplx a, cplx b) {
  return make_float2(a.x*b.x - a.y*b.y, a.x*b.y + a.y*b.x);
}
__device__ __forceinline__ cplx cadd(cplx a, cplx b) {
  return make_float2(a.x + b.x, a.y + b.y);
}

// --------------------------------------------------------------------------
// K_prep: fused U = Rz*Ry*Rx per (layer,qubit); layer-0 product tables;
// zero the accumulators (dots[128], xn2, L2).
// --------------------------------------------------------------------------
__global__ void k_prep(const float* __restrict__ qp, cplx* __restrict__ Ug,
                       cplx* __restrict__ prodLow, cplx* __restrict__ prodHigh,
                       float* __restrict__ accs) {
  __shared__ cplx Ush[54][4];
  int t = threadIdx.x;
  if (t < 132) accs[t] = 0.0f;
  if (t < 54) {
    float a = qp[t*3+0], b = qp[t*3+1], c = qp[t*3+2];
    float ca = cosf(0.5f*a), sa = sinf(0.5f*a);
    float cb = cosf(0.5f*b), sb = sinf(0.5f*b);
    float cc = cosf(0.5f*c), sc = sinf(0.5f*c);
    // M = Ry*Rx
    cplx m00 = make_float2( cb*ca,  sb*sa);
    cplx m01 = make_float2(-sb*ca, -cb*sa);
    cplx m10 = make_float2( sb*ca, -cb*sa);
    cplx m11 = make_float2( cb*ca, -sb*sa);
    // U = Rz*M : row0 *= e^{-ic/2}, row1 *= e^{+ic/2}
    cplx e0 = make_float2(cc, -sc), e1 = make_float2(cc, sc);
    cplx u00 = cmul(e0, m00), u01 = cmul(e0, m01);
    cplx u10 = cmul(e1, m10), u11 = cmul(e1, m11);
    Ush[t][0] = u00; Ush[t][1] = u01; Ush[t][2] = u10; Ush[t][3] = u11;
    Ug[t*4+0] = u00; Ug[t*4+1] = u01; Ug[t*4+2] = u10; Ug[t*4+3] = u11;
  }
  __syncthreads();
  // layer-0 product state: amp(i) = prod_p U0[17-p][bit_p(i)][0]
  for (int m = t; m < 4096; m += blockDim.x) {
    cplx v = make_float2(1.f, 0.f);
    for (int p = 0; p < 12; ++p) {
      int q = 17 - p;
      cplx f = ((m >> p) & 1) ? Ush[q][2] : Ush[q][0];
      v = cmul(v, f);
    }
    prodLow[m] = v;
  }
  if (t < 64) {
    cplx v = make_float2(1.f, 0.f);
    for (int p = 12; p < 18; ++p) {
      int q = 17 - p;
      cplx f = ((t >> (p - 12)) & 1) ? Ush[q][2] : Ush[q][0];
      v = cmul(v, f);
    }
    prodHigh[t] = v;
  }
}

// --------------------------------------------------------------------------
// K_enc: h = relu(state@w1+b1); enc = h@w2+b2; xc = amp*exp(i*ph).
// 1024 blocks x 256 threads, 4 rows/block; thread (r,j) computes h[r][j]
// with 4 independent accumulators (breaks the serial FMA chain). w1 is
// L2-resident (64 KB); 64 MB total L2 reads ~ 2us.
// --------------------------------------------------------------------------
__global__ __launch_bounds__(256) void k_enc(
    const float* __restrict__ state, const float* __restrict__ w1,
    const float* __restrict__ b1, const float* __restrict__ w2,
    const float* __restrict__ b2, float* __restrict__ xRe,
    float* __restrict__ xIm, float* __restrict__ xn2) {
  __shared__ float sState[4][256];
  __shared__ float hS[4][64];
  __shared__ float encS[4][36];
  __shared__ float wsum[4];
  int t = threadIdx.x;
  int r = t >> 6, j = t & 63;
  // stage 4 rows (1024 floats) via one float4 per thread (coalesced)
  const float4* st4 =
      reinterpret_cast<const float4*>(state + (size_t)blockIdx.x * 1024);
  reinterpret_cast<float4*>(&sState[0][0])[t] = st4[t];
  __syncthreads();
  float a0 = 0.f, a1 = 0.f, a2 = 0.f, a3 = 0.f;
#pragma unroll 4
  for (int k = 0; k < 256; k += 4) {
    a0 = fmaf(sState[r][k+0], w1[(k+0)*64 + j], a0);
    a1 = fmaf(sState[r][k+1], w1[(k+1)*64 + j], a1);
    a2 = fmaf(sState[r][k+2], w1[(k+2)*64 + j], a2);
    a3 = fmaf(sState[r][k+3], w1[(k+3)*64 + j], a3);
  }
  hS[r][j] = fmaxf((a0 + a1) + (a2 + a3) + b1[j], 0.f);
  __syncthreads();
  if (j < 36) {
    float a = b2[j];
#pragma unroll 8
    for (int k = 0; k < 64; ++k) a = fmaf(hS[r][k], w2[k*36 + j], a);
    encS[r][j] = a;
  }
  __syncthreads();
  float lsum = 0.f;
  if (j < 18) {
    float amp = encS[r][j], ph = encS[r][18 + j];
    float sp, cp;
    sincosf(ph, &sp, &cp);
    int row = blockIdx.x*4 + r;
    xRe[row*18 + j] = amp * cp;
    xIm[row*18 + j] = amp * sp;
    lsum = amp * amp;
  }
  for (int off = 32; off > 0; off >>= 1) lsum += __shfl_down(lsum, off, 64);
  if (j == 0) wsum[r] = lsum;
  __syncthreads();
  if (t == 0) atomicAdd(xn2, wsum[0] + wsum[1] + wsum[2] + wsum[3]);
}

// --------------------------------------------------------------------------
// K_sweepA: gates on low 12 bits (qubits 6..17) in a 4096-elem LDS tile.
// mode 0: input = layer-0 product state gathered through perm P.
// mode 1: input = svIn[P(i)] (fuses previous layer's CNOT chain).
// 512 threads/block (8 waves) to shorten the per-block critical path.
// --------------------------------------------------------------------------
__global__ __launch_bounds__(512) void k_sweepA(
    const cplx* __restrict__ Ug, const cplx* __restrict__ prodLow,
    const cplx* __restrict__ prodHigh, const cplx* __restrict__ svIn,
    cplx* __restrict__ svOut, int layer, int mode) {
  __shared__ float sRe[4096], sIm[4096];
  int t = threadIdx.x;
  int base = blockIdx.x << 12;
  for (int e = t; e < 4096; e += 512) {
    int i = base + e;
    int src = (i ^ (i << 1)) & PMASK;   // CNOT-chain permutation
    cplx v;
    if (mode == 0) v = cmul(prodHigh[src >> 12], prodLow[src & 4095]);
    else           v = svIn[src];
    sRe[e] = v.x; sIm[e] = v.y;
  }
  __syncthreads();
  for (int p = 0; p < 12; ++p) {
    int q = 17 - p;
    const cplx* U = Ug + (layer*18 + q)*4;
    cplx u00 = U[0], u01 = U[1], u10 = U[2], u11 = U[3];
    for (int k = t; k < 2048; k += 512) {
      int i0 = ((k >> p) << (p + 1)) | (k & ((1 << p) - 1));
      int i1 = i0 | (1 << p);
      cplx a = make_float2(sRe[i0], sIm[i0]);
      cplx b = make_float2(sRe[i1], sIm[i1]);
      cplx na = cadd(cmul(u00, a), cmul(u01, b));
      cplx nb = cadd(cmul(u10, a), cmul(u11, b));
      sRe[i0] = na.x; sIm[i0] = na.y;
      sRe[i1] = nb.x; sIm[i1] = nb.y;
    }
    __syncthreads();
  }
  for (int e = t; e < 4096; e += 512)
    svOut[base + e] = make_float2(sRe[e], sIm[e]);
}

// --------------------------------------------------------------------------
// K_sweepB: gates on high 6 bits (qubits 0..5). Tile = 64 h-values x 64
// low-indices in LDS; in-place on sv (tiles partition by low index).
// --------------------------------------------------------------------------
__global__ __launch_bounds__(512) void k_sweepB(const cplx* __restrict__ Ug,
                                                cplx* __restrict__ sv,
                                                int layer) {
  __shared__ float tRe[4096], tIm[4096];  // [h*64 + l]
  int t = threadIdx.x;
  int lbase = blockIdx.x << 6;
  for (int m = t; m < 4096; m += 512) {
    int h = m >> 6, l = m & 63;
    cplx v = sv[h*4096 + lbase + l];
    tRe[m] = v.x; tIm[m] = v.y;
  }
  __syncthreads();
  for (int ph = 0; ph < 6; ++ph) {
    int p = 12 + ph, q = 17 - p;
    const cplx* U = Ug + (layer*18 + q)*4;
    cplx u00 = U[0], u01 = U[1], u10 = U[2], u11 = U[3];
    for (int k = t; k < 2048; k += 512) {
      int kh = k >> 6, l = k & 63;
      int h0 = ((kh >> ph) << (ph + 1)) | (kh & ((1 << ph) - 1));
      int h1 = h0 | (1 << ph);
      int i0 = h0*64 + l, i1 = h1*64 + l;
      cplx a = make_float2(tRe[i0], tIm[i0]);
      cplx b = make_float2(tRe[i1], tIm[i1]);
      cplx na = cadd(cmul(u00, a), cmul(u01, b));
      cplx nb = cadd(cmul(u10, a), cmul(u11, b));
      tRe[i0] = na.x; tIm[i0] = na.y;
      tRe[i1] = nb.x; tIm[i1] = nb.y;
    }
    __syncthreads();
  }
  for (int m = t; m < 4096; m += 512) {
    int h = m >> 6, l = m & 63;
    sv[h*4096 + lbase + l] = make_float2(tRe[m], tIm[m]);
  }
}

// --------------------------------------------------------------------------
// K_combine: final perm gather + add normalized x + build cl (re plane then
// im plane, unnormalized) + accumulate L2 = ||sv||^2.
// --------------------------------------------------------------------------
__global__ __launch_bounds__(256) void k_combine(
    const cplx* __restrict__ svIn, const float* __restrict__ xRe,
    const float* __restrict__ xIm, const float* __restrict__ xn2,
    float* __restrict__ cl, float* __restrict__ L2acc) {
  int t = threadIdx.x;
  float xs = xn2[0];
  float invXn = (xs > 0.f) ? (1.0f / sqrtf(xs)) : 1.0f;
  float lsum = 0.f;
  for (int u = 0; u < 4; ++u) {
    int i = blockIdx.x*1024 + u*256 + t;
    int src = (i ^ (i << 1)) & PMASK;
    cplx v = svIn[src];
    if (i < XLEN) {
      v.x = fmaf(xRe[i], invXn, v.x);
      v.y = fmaf(xIm[i], invXn, v.y);
    }
    cl[i] = v.x;
    cl[DIMSZ + i] = v.y;
    lsum += v.x*v.x + v.y*v.y;
  }
  for (int off = 32; off > 0; off >>= 1) lsum += __shfl_down(lsum, off, 64);
  if ((t & 63) == 0) atomicAdd(L2acc, lsum);
}

// --------------------------------------------------------------------------
// K_matvec: dots[mat*64+c] = sum_r cl[r]*W[r,c] / L. HBM-bound 268 MB
// weight stream. 1024 WGs: blockIdx&1 = matrix, blockIdx>>1 = 1024-row chunk.
// Thread t: cols 4*(t&15)..+3, rows (t>>4) + 16*pass. float4 coalesced.
// --------------------------------------------------------------------------
__global__ __launch_bounds__(256) void k_matvec(
    const float* __restrict__ cl, const float* __restrict__ Wdec,
    const float* __restrict__ Wval, const float* __restrict__ L2acc,
    float* __restrict__ dots) {
  __shared__ float clS[1024];
  __shared__ float red[1024];
  int t = threadIdx.x;
  int mat = blockIdx.x & 1;
  size_t r0 = (size_t)(blockIdx.x >> 1) * 1024;
  const float4* cl4 = reinterpret_cast<const float4*>(cl + r0);
  reinterpret_cast<float4*>(clS)[t] = cl4[t];
  __syncthreads();
  const float* W = (mat ? Wval : Wdec) + r0*64 + (size_t)((t & 15)*4);
  int ro = t >> 4;
  float ax = 0.f, ay = 0.f, az = 0.f, aw = 0.f;
#pragma unroll 4
  for (int pass = 0; pass < 64; ++pass) {
    int r = (pass << 4) + ro;
    const float4 w = *reinterpret_cast<const float4*>(W + (size_t)r*64);
    float s = clS[r];
    ax = fmaf(s, w.x, ax);
    ay = fmaf(s, w.y, ay);
    az = fmaf(s, w.z, az);
    aw = fmaf(s, w.w, aw);
  }
  red[t*4+0] = ax; red[t*4+1] = ay; red[t*4+2] = az; red[t*4+3] = aw;
  __syncthreads();
  if (t < 64) {
    int ci0 = t >> 2, jj = t & 3;
    float sum = 0.f;
    for (int r2 = 0; r2 < 16; ++r2) sum += red[(r2*16 + ci0)*4 + jj];
    float invL = 1.0f / sqrtf(L2acc[0]);
    atomicAdd(&dots[mat*64 + t], sum * invL);
  }
}

// --------------------------------------------------------------------------
// K_final: hidden relu + tiny second layers -> 19 outputs.
// --------------------------------------------------------------------------
__global__ void k_final(const float* __restrict__ dots,
                        const float* __restrict__ db1,
                        const float* __restrict__ dw2,
                        const float* __restrict__ db2,
                        const float* __restrict__ vb1,
                        const float* __restrict__ vw2,
                        const float* __restrict__ vb2,
                        float* __restrict__ out) {
  __shared__ float hd[64], hv[64];
  int t = threadIdx.x;
  hd[t] = fmaxf(dots[t] + db1[t], 0.f);
  hv[t] = fmaxf(dots[64 + t] + vb1[t], 0.f);
  __syncthreads();
  if (t < 18) {
    float s = db2[t];
    for (int k = 0; k < 64; ++k) s = fmaf(hd[k], dw2[k*18 + t], s);
    out[t] = s;
  }
  if (t == 20) {
    float s = vb2[0];
    for (int k = 0; k < 64; ++k) s = fmaf(hv[k], vw2[k], s);
    out[18] = s;
  }
}

extern "C" void kernel_launch(void* const* d_in, const int* in_sizes, int n_in,
                              void* d_out, int out_size, void* d_ws,
                              size_t ws_size, hipStream_t stream) {
  const float* state  = (const float*)d_in[0];
  const float* enc_w1 = (const float*)d_in[1];
  const float* enc_b1 = (const float*)d_in[2];
  const float* enc_w2 = (const float*)d_in[3];
  const float* enc_b2 = (const float*)d_in[4];
  const float* qparams= (const float*)d_in[5];
  const float* dec_w1 = (const float*)d_in[6];
  const float* dec_b1 = (const float*)d_in[7];
  const float* dec_w2 = (const float*)d_in[8];
  const float* dec_b2 = (const float*)d_in[9];
  const float* val_w1 = (const float*)d_in[10];
  const float* val_b1 = (const float*)d_in[11];
  const float* val_w2 = (const float*)d_in[12];
  const float* val_b2 = (const float*)d_in[13];

  float* wsf = (float*)d_ws;
  // ws layout (floats): total ~1.74M floats (~6.9 MB)
  float* dots     = wsf;                         // 128
  float* xn2      = wsf + 128;                   // 1
  float* L2acc    = wsf + 129;                   // 1
  cplx*  Ug       = (cplx*)(wsf + 256);          // 216 cplx
  cplx*  prodLow  = (cplx*)(wsf + 1024);         // 4096 cplx
  cplx*  prodHigh = (cplx*)(wsf + 9216);         // 64 cplx
  float* xRe      = wsf + 16384;                 // 73728
  float* xIm      = wsf + 90112;                 // 73728
  cplx*  svA      = (cplx*)(wsf + 163840);       // 262144 cplx
  cplx*  svB      = (cplx*)(wsf + 688128);       // 262144 cplx
  float* cl       = wsf + 1212416;               // 524288

  hipLaunchKernelGGL(k_prep, dim3(1), dim3(256), 0, stream,
                     qparams, Ug, prodLow, prodHigh, wsf);
  hipLaunchKernelGGL(k_enc, dim3(1024), dim3(256), 0, stream,
                     state, enc_w1, enc_b1, enc_w2, enc_b2, xRe, xIm, xn2);
  // layer 2 gates (layer index 1); input = permuted layer-1 product state
  hipLaunchKernelGGL(k_sweepA, dim3(64), dim3(512), 0, stream,
                     Ug, prodLow, prodHigh, (const cplx*)nullptr, svA, 1, 0);
  hipLaunchKernelGGL(k_sweepB, dim3(64), dim3(512), 0, stream, Ug, svA, 1);
  // layer 3 gates (layer index 2); input = svA gathered through perm P
  hipLaunchKernelGGL(k_sweepA, dim3(64), dim3(512), 0, stream,
                     Ug, prodLow, prodHigh, (const cplx*)svA, svB, 2, 1);
  hipLaunchKernelGGL(k_sweepB, dim3(64), dim3(512), 0, stream, Ug, svB, 2);
  hipLaunchKernelGGL(k_combine, dim3(256), dim3(256), 0, stream,
                     svB, xRe, xIm, xn2, cl, L2acc);
  hipLaunchKernelGGL(k_matvec, dim3(1024), dim3(256), 0, stream,
                     cl, dec_w1, val_w1, L2acc, dots);
  hipLaunchKernelGGL(k_final, dim3(1), dim3(64), 0, stream,
                     dots, dec_b1, dec_w2, dec_b2, val_b1, val_w2, val_b2,
                     (float*)d_out);
}

// Round 3
// 387.452 us; speedup vs baseline: 1.5517x; 1.0355x over previous
//
#include <hip/hip_runtime.h>
#include <cstdint>
#include <cstddef>

// ---------------------------------------------------------------------------
// QuantumRLAgent: 18-qubit statevector sim + MLPs.
// Batch collapses into ONE statevector. Dominant cost: two 524288x64 fp32
// matvecs (268 MB weight stream; LLC holds ~half between replays -> ~133 MB
// HBM). Circuit: fused 1q gates; CNOT chain == perm P(i)=(i^(i<<1))&0x3FFFF
// fused into next kernel's gather; layer-1 analytic product state.
//
// R2 -> R3: matvec was 107us @1.27TB/s: latency-limited (too few outstanding
// loads) + 65536 hot atomics (WRITE_SIZE=256KB). Now: unroll-8 load batches,
// 2048 blocks, 32-slot replicated atomics. Sweeps re-tiled 64 -> 256 blocks.
// ---------------------------------------------------------------------------

#define NQb   18
#define DIMSZ 262144      // 2^18
#define PMASK 0x3FFFF
#define XLEN  73728       // 4096*18

typedef float2 cplx;

__device__ __forceinline__ cplx cmul(cplx a, cplx b) {
  return make_float2(a.x*b.x - a.y*b.y, a.x*b.y + a.y*b.x);
}
__device__ __forceinline__ cplx cadd(cplx a, cplx b) {
  return make_float2(a.x + b.x, a.y + b.y);
}

// --------------------------------------------------------------------------
// K_prep: fused U = Rz*Ry*Rx per (layer,qubit); layer-0 product tables;
// zero accumulators (dots_rep[32][128] + xn2 + L2acc = 4098 floats).
// --------------------------------------------------------------------------
__global__ void k_prep(const float* __restrict__ qp, cplx* __restrict__ Ug,
                       cplx* __restrict__ prodLow, cplx* __restrict__ prodHigh,
                       float* __restrict__ accs) {
  __shared__ cplx Ush[54][4];
  int t = threadIdx.x;
  for (int k = t; k < 4352; k += 256) accs[k] = 0.0f;
  if (t < 54) {
    float a = qp[t*3+0], b = qp[t*3+1], c = qp[t*3+2];
    float ca = cosf(0.5f*a), sa = sinf(0.5f*a);
    float cb = cosf(0.5f*b), sb = sinf(0.5f*b);
    float cc = cosf(0.5f*c), sc = sinf(0.5f*c);
    // M = Ry*Rx
    cplx m00 = make_float2( cb*ca,  sb*sa);
    cplx m01 = make_float2(-sb*ca, -cb*sa);
    cplx m10 = make_float2( sb*ca, -cb*sa);
    cplx m11 = make_float2( cb*ca, -sb*sa);
    // U = Rz*M : row0 *= e^{-ic/2}, row1 *= e^{+ic/2}
    cplx e0 = make_float2(cc, -sc), e1 = make_float2(cc, sc);
    cplx u00 = cmul(e0, m00), u01 = cmul(e0, m01);
    cplx u10 = cmul(e1, m10), u11 = cmul(e1, m11);
    Ush[t][0] = u00; Ush[t][1] = u01; Ush[t][2] = u10; Ush[t][3] = u11;
    Ug[t*4+0] = u00; Ug[t*4+1] = u01; Ug[t*4+2] = u10; Ug[t*4+3] = u11;
  }
  __syncthreads();
  // layer-0 product state: amp(i) = prod_p U0[17-p][bit_p(i)][0]
  for (int m = t; m < 4096; m += blockDim.x) {
    cplx v = make_float2(1.f, 0.f);
    for (int p = 0; p < 12; ++p) {
      int q = 17 - p;
      cplx f = ((m >> p) & 1) ? Ush[q][2] : Ush[q][0];
      v = cmul(v, f);
    }
    prodLow[m] = v;
  }
  if (t < 64) {
    cplx v = make_float2(1.f, 0.f);
    for (int p = 12; p < 18; ++p) {
      int q = 17 - p;
      cplx f = ((t >> (p - 12)) & 1) ? Ush[q][2] : Ush[q][0];
      v = cmul(v, f);
    }
    prodHigh[t] = v;
  }
}

// --------------------------------------------------------------------------
// K_enc: h = relu(state@w1+b1); enc = h@w2+b2; xc = amp*exp(i*ph).
// 1024 blocks x 256 threads, 4 rows/block, 4 independent accumulators.
// --------------------------------------------------------------------------
__global__ __launch_bounds__(256) void k_enc(
    const float* __restrict__ state, const float* __restrict__ w1,
    const float* __restrict__ b1, const float* __restrict__ w2,
    const float* __restrict__ b2, float* __restrict__ xRe,
    float* __restrict__ xIm, float* __restrict__ xn2) {
  __shared__ float sState[4][256];
  __shared__ float hS[4][64];
  __shared__ float encS[4][36];
  __shared__ float wsum[4];
  int t = threadIdx.x;
  int r = t >> 6, j = t & 63;
  const float4* st4 =
      reinterpret_cast<const float4*>(state + (size_t)blockIdx.x * 1024);
  reinterpret_cast<float4*>(&sState[0][0])[t] = st4[t];
  __syncthreads();
  float a0 = 0.f, a1 = 0.f, a2 = 0.f, a3 = 0.f;
#pragma unroll 4
  for (int k = 0; k < 256; k += 4) {
    a0 = fmaf(sState[r][k+0], w1[(k+0)*64 + j], a0);
    a1 = fmaf(sState[r][k+1], w1[(k+1)*64 + j], a1);
    a2 = fmaf(sState[r][k+2], w1[(k+2)*64 + j], a2);
    a3 = fmaf(sState[r][k+3], w1[(k+3)*64 + j], a3);
  }
  hS[r][j] = fmaxf((a0 + a1) + (a2 + a3) + b1[j], 0.f);
  __syncthreads();
  if (j < 36) {
    float a = b2[j];
#pragma unroll 8
    for (int k = 0; k < 64; ++k) a = fmaf(hS[r][k], w2[k*36 + j], a);
    encS[r][j] = a;
  }
  __syncthreads();
  float lsum = 0.f;
  if (j < 18) {
    float amp = encS[r][j], ph = encS[r][18 + j];
    float sp, cp;
    sincosf(ph, &sp, &cp);
    int row = blockIdx.x*4 + r;
    xRe[row*18 + j] = amp * cp;
    xIm[row*18 + j] = amp * sp;
    lsum = amp * amp;
  }
  for (int off = 32; off > 0; off >>= 1) lsum += __shfl_down(lsum, off, 64);
  if (j == 0) wsum[r] = lsum;
  __syncthreads();
  if (t == 0) atomicAdd(xn2, wsum[0] + wsum[1] + wsum[2] + wsum[3]);
}

// --------------------------------------------------------------------------
// K_gatesLow: gates on bits 0..9 (qubits 17..8). 256 blocks x 512 thr,
// contiguous 1024-elem tiles in LDS. Input gathered through perm P.
// mode 0: layer-0 product state; mode 1: svIn[P(i)].
// --------------------------------------------------------------------------
__global__ __launch_bounds__(512) void k_gatesLow(
    const cplx* __restrict__ Ug, const cplx* __restrict__ prodLow,
    const cplx* __restrict__ prodHigh, const cplx* __restrict__ svIn,
    cplx* __restrict__ svOut, int layer, int mode) {
  __shared__ float sRe[1024], sIm[1024];
  int t = threadIdx.x;
  int base = blockIdx.x << 10;
  for (int e = t; e < 1024; e += 512) {
    int i = base + e;
    int src = (i ^ (i << 1)) & PMASK;   // CNOT-chain permutation
    cplx v;
    if (mode == 0) v = cmul(prodHigh[src >> 12], prodLow[src & 4095]);
    else           v = svIn[src];
    sRe[e] = v.x; sIm[e] = v.y;
  }
  __syncthreads();
  for (int p = 0; p < 10; ++p) {
    int q = 17 - p;
    const cplx* U = Ug + (layer*18 + q)*4;
    cplx u00 = U[0], u01 = U[1], u10 = U[2], u11 = U[3];
    if (t < 512) {
      int k = t;
      int i0 = ((k >> p) << (p + 1)) | (k & ((1 << p) - 1));
      int i1 = i0 | (1 << p);
      cplx a = make_float2(sRe[i0], sIm[i0]);
      cplx b = make_float2(sRe[i1], sIm[i1]);
      cplx na = cadd(cmul(u00, a), cmul(u01, b));
      cplx nb = cadd(cmul(u10, a), cmul(u11, b));
      sRe[i0] = na.x; sIm[i0] = na.y;
      sRe[i1] = nb.x; sIm[i1] = nb.y;
    }
    __syncthreads();
  }
  for (int e = t; e < 1024; e += 512)
    svOut[base + e] = make_float2(sRe[e], sIm[e]);
}

// --------------------------------------------------------------------------
// K_gatesHigh: gates on bits 10..17 (qubits 7..0). 256 blocks x 512 thr.
// Tile = 256 h-values (bits 10..17) x 4 l-values; in-place (tiles partition
// by l-chunk). LDS index m = h*4 + j.
// --------------------------------------------------------------------------
__global__ __launch_bounds__(512) void k_gatesHigh(
    const cplx* __restrict__ Ug, cplx* __restrict__ sv, int layer) {
  __shared__ float tRe[1024], tIm[1024];
  int t = threadIdx.x;
  int l0 = blockIdx.x << 2;
  for (int e = t; e < 1024; e += 512) {
    int h = e >> 2, j = e & 3;
    cplx v = sv[h*1024 + l0 + j];
    tRe[e] = v.x; tIm[e] = v.y;
  }
  __syncthreads();
  for (int ph = 0; ph < 8; ++ph) {
    int q = 7 - ph;                    // bit p = 10+ph, qubit q = 17-p
    const cplx* U = Ug + (layer*18 + q)*4;
    cplx u00 = U[0], u01 = U[1], u10 = U[2], u11 = U[3];
    if (t < 512) {
      int kh = t >> 2, j = t & 3;
      int h0 = ((kh >> ph) << (ph + 1)) | (kh & ((1 << ph) - 1));
      int h1 = h0 | (1 << ph);
      int i0 = h0*4 + j, i1 = h1*4 + j;
      cplx a = make_float2(tRe[i0], tIm[i0]);
      cplx b = make_float2(tRe[i1], tIm[i1]);
      cplx na = cadd(cmul(u00, a), cmul(u01, b));
      cplx nb = cadd(cmul(u10, a), cmul(u11, b));
      tRe[i0] = na.x; tIm[i0] = na.y;
      tRe[i1] = nb.x; tIm[i1] = nb.y;
    }
    __syncthreads();
  }
  for (int e = t; e < 1024; e += 512) {
    int h = e >> 2, j = e & 3;
    sv[h*1024 + l0 + j] = make_float2(tRe[e], tIm[e]);
  }
}

// --------------------------------------------------------------------------
// K_combine: final perm gather + add normalized x + build cl (re plane,
// im plane; unnormalized) + accumulate L2 = ||sv||^2.
// --------------------------------------------------------------------------
__global__ __launch_bounds__(256) void k_combine(
    const cplx* __restrict__ svIn, const float* __restrict__ xRe,
    const float* __restrict__ xIm, const float* __restrict__ xn2,
    float* __restrict__ cl, float* __restrict__ L2acc) {
  int t = threadIdx.x;
  float xs = xn2[0];
  float invXn = (xs > 0.f) ? (1.0f / sqrtf(xs)) : 1.0f;
  float lsum = 0.f;
  for (int u = 0; u < 4; ++u) {
    int i = blockIdx.x*1024 + u*256 + t;
    int src = (i ^ (i << 1)) & PMASK;
    cplx v = svIn[src];
    if (i < XLEN) {
      v.x = fmaf(xRe[i], invXn, v.x);
      v.y = fmaf(xIm[i], invXn, v.y);
    }
    cl[i] = v.x;
    cl[DIMSZ + i] = v.y;
    lsum += v.x*v.x + v.y*v.y;
  }
  for (int off = 32; off > 0; off >>= 1) lsum += __shfl_down(lsum, off, 64);
  if ((t & 63) == 0) atomicAdd(L2acc, lsum);
}

// --------------------------------------------------------------------------
// K_matvec: partial[slot][mat*64+c] += sum_r cl[r]*W[r,c] over a 512-row
// chunk. 2048 blocks (1024 chunks x 2 mats). Unroll-8: all 8 float4 loads
// issued before any FMA -> 8 KB in flight per wave. 32 replicated atomic
// slots kill the hot-line serialization seen in R2 (WRITE_SIZE=256KB of
// single-dword RMWs).
// --------------------------------------------------------------------------
__global__ __launch_bounds__(256, 4) void k_matvec(
    const float* __restrict__ cl, const float* __restrict__ Wdec,
    const float* __restrict__ Wval, float* __restrict__ dots_rep) {
  __shared__ float clS[512];
  __shared__ float red[1024];
  int t = threadIdx.x;
  int mat = blockIdx.x & 1;
  int chunk = blockIdx.x >> 1;             // 0..1023
  size_t r0 = (size_t)chunk * 512;
  if (t < 128)
    reinterpret_cast<float4*>(clS)[t] =
        reinterpret_cast<const float4*>(cl + r0)[t];
  __syncthreads();
  const float* W = (mat ? Wval : Wdec) + r0*64 + (size_t)((t & 15)*4);
  int ro = t >> 4;
  float ax = 0.f, ay = 0.f, az = 0.f, aw = 0.f;
  for (int g = 0; g < 4; ++g) {
    float4 w[8];
    float  s[8];
#pragma unroll
    for (int u = 0; u < 8; ++u) {
      int r = g*128 + u*16 + ro;
      w[u] = *reinterpret_cast<const float4*>(W + (size_t)r*64);
      s[u] = clS[r];
    }
#pragma unroll
    for (int u = 0; u < 8; ++u) {
      ax = fmaf(s[u], w[u].x, ax);
      ay = fmaf(s[u], w[u].y, ay);
      az = fmaf(s[u], w[u].z, az);
      aw = fmaf(s[u], w[u].w, aw);
    }
  }
  red[t*4+0] = ax; red[t*4+1] = ay; red[t*4+2] = az; red[t*4+3] = aw;
  __syncthreads();
  if (t < 64) {
    int ci0 = t >> 2, jj = t & 3;
    float sum = 0.f;
#pragma unroll
    for (int r2 = 0; r2 < 16; ++r2) sum += red[(r2*16 + ci0)*4 + jj];
    int slot = chunk & 31;
    atomicAdd(&dots_rep[slot*128 + mat*64 + t], sum);
  }
}

// --------------------------------------------------------------------------
// K_final: sum 32 slots, apply invL, hidden relu + tiny second layers.
// --------------------------------------------------------------------------
__global__ void k_final(const float* __restrict__ dots_rep,
                        const float* __restrict__ L2acc,
                        const float* __restrict__ db1,
                        const float* __restrict__ dw2,
                        const float* __restrict__ db2,
                        const float* __restrict__ vb1,
                        const float* __restrict__ vw2,
                        const float* __restrict__ vb2,
                        float* __restrict__ out) {
  __shared__ float hd[64], hv[64];
  int t = threadIdx.x;
  float sd = 0.f, sva = 0.f;
#pragma unroll
  for (int s = 0; s < 32; ++s) {
    sd  += dots_rep[s*128 + t];
    sva += dots_rep[s*128 + 64 + t];
  }
  float invL = 1.0f / sqrtf(L2acc[0]);
  hd[t] = fmaxf(sd * invL + db1[t], 0.f);
  hv[t] = fmaxf(sva * invL + vb1[t], 0.f);
  __syncthreads();
  if (t < 18) {
    float s = db2[t];
    for (int k = 0; k < 64; ++k) s = fmaf(hd[k], dw2[k*18 + t], s);
    out[t] = s;
  }
  if (t == 20) {
    float s = vb2[0];
    for (int k = 0; k < 64; ++k) s = fmaf(hv[k], vw2[k], s);
    out[18] = s;
  }
}

extern "C" void kernel_launch(void* const* d_in, const int* in_sizes, int n_in,
                              void* d_out, int out_size, void* d_ws,
                              size_t ws_size, hipStream_t stream) {
  const float* state  = (const float*)d_in[0];
  const float* enc_w1 = (const float*)d_in[1];
  const float* enc_b1 = (const float*)d_in[2];
  const float* enc_w2 = (const float*)d_in[3];
  const float* enc_b2 = (const float*)d_in[4];
  const float* qparams= (const float*)d_in[5];
  const float* dec_w1 = (const float*)d_in[6];
  const float* dec_b1 = (const float*)d_in[7];
  const float* dec_w2 = (const float*)d_in[8];
  const float* dec_b2 = (const float*)d_in[9];
  const float* val_w1 = (const float*)d_in[10];
  const float* val_b1 = (const float*)d_in[11];
  const float* val_w2 = (const float*)d_in[12];
  const float* val_b2 = (const float*)d_in[13];

  float* wsf = (float*)d_ws;
  // ws layout (floats):
  float* dots_rep = wsf;                         // 32*128 = 4096
  float* xn2      = wsf + 4096;                  // 1
  float* L2acc    = wsf + 4097;                  // 1
  cplx*  Ug       = (cplx*)(wsf + 4352);         // 216 cplx (432 f)
  cplx*  prodLow  = (cplx*)(wsf + 8192);         // 4096 cplx (8192 f)
  cplx*  prodHigh = (cplx*)(wsf + 16384);        // 64 cplx (128 f)
  float* xRe      = wsf + 16640;                 // 73728
  float* xIm      = wsf + 90368;                 // 73728
  cplx*  svA      = (cplx*)(wsf + 164096);       // 262144 cplx
  cplx*  svB      = (cplx*)(wsf + 688384);       // 262144 cplx
  float* cl       = wsf + 1212672;               // 524288  (ends 1736960)

  hipLaunchKernelGGL(k_prep, dim3(1), dim3(256), 0, stream,
                     qparams, Ug, prodLow, prodHigh, wsf);
  hipLaunchKernelGGL(k_enc, dim3(1024), dim3(256), 0, stream,
                     state, enc_w1, enc_b1, enc_w2, enc_b2, xRe, xIm, xn2);
  // layer index 1: input = permuted layer-0 product state
  hipLaunchKernelGGL(k_gatesLow, dim3(256), dim3(512), 0, stream,
                     Ug, prodLow, prodHigh, (const cplx*)nullptr, svA, 1, 0);
  hipLaunchKernelGGL(k_gatesHigh, dim3(256), dim3(512), 0, stream, Ug, svA, 1);
  // layer index 2: input = svA gathered through perm P
  hipLaunchKernelGGL(k_gatesLow, dim3(256), dim3(512), 0, stream,
                     Ug, prodLow, prodHigh, (const cplx*)svA, svB, 2, 1);
  hipLaunchKernelGGL(k_gatesHigh, dim3(256), dim3(512), 0, stream, Ug, svB, 2);
  hipLaunchKernelGGL(k_combine, dim3(256), dim3(256), 0, stream,
                     svB, xRe, xIm, xn2, cl, L2acc);
  hipLaunchKernelGGL(k_matvec, dim3(2048), dim3(256), 0, stream,
                     cl, dec_w1, val_w1, dots_rep);
  hipLaunchKernelGGL(k_final, dim3(1), dim3(64), 0, stream,
                     dots_rep, L2acc, dec_b1, dec_w2, dec_b2,
                     val_b1, val_w2, val_b2, (float*)d_out);
}

// Round 4
// 387.176 us; speedup vs baseline: 1.5528x; 1.0007x over previous
//
#include <hip/hip_runtime.h>
#include <cstdint>
#include <cstddef>

// ---------------------------------------------------------------------------
// QuantumRLAgent: 18-qubit statevector sim + MLPs.
// Batch collapses into ONE statevector. Dominant cost: two 524288x64 fp32
// matvecs (268 MB weight stream; LLC serves ~half across graph replays ->
// ~133 MB HBM fetch). Circuit: fused 1q gates; CNOT chain == perm
// P(i)=(i^(i<<1))&0x3FFFF fused into next kernel's gather; layer-1 analytic
// product state.
//
// R3 -> R4: matvec stuck at 101us/1.34TB/s. VGPR=32 proved the compiler
// re-rolled the w[8] array batch into load->vmcnt(0)->fma (1 outstanding
// load/wave -> ~2.6TB/s demand ceiling, matches measurement). Fix: 8
// individually-NAMED float4 loads per group, no launch_bounds floor ->
// compiler emits 8 back-to-back global_load_dwordx4 with descending vmcnt.
// ---------------------------------------------------------------------------

#define NQb   18
#define DIMSZ 262144      // 2^18
#define PMASK 0x3FFFF
#define XLEN  73728       // 4096*18

typedef float2 cplx;

__device__ __forceinline__ cplx cmul(cplx a, cplx b) {
  return make_float2(a.x*b.x - a.y*b.y, a.x*b.y + a.y*b.x);
}
__device__ __forceinline__ cplx cadd(cplx a, cplx b) {
  return make_float2(a.x + b.x, a.y + b.y);
}

// --------------------------------------------------------------------------
// K_prep: fused U = Rz*Ry*Rx per (layer,qubit); layer-0 product tables;
// zero accumulators (dots_rep[32][128] + xn2 + L2acc).
// --------------------------------------------------------------------------
__global__ void k_prep(const float* __restrict__ qp, cplx* __restrict__ Ug,
                       cplx* __restrict__ prodLow, cplx* __restrict__ prodHigh,
                       float* __restrict__ accs) {
  __shared__ cplx Ush[54][4];
  int t = threadIdx.x;
  for (int k = t; k < 4352; k += 256) accs[k] = 0.0f;
  if (t < 54) {
    float a = qp[t*3+0], b = qp[t*3+1], c = qp[t*3+2];
    float ca = cosf(0.5f*a), sa = sinf(0.5f*a);
    float cb = cosf(0.5f*b), sb = sinf(0.5f*b);
    float cc = cosf(0.5f*c), sc = sinf(0.5f*c);
    // M = Ry*Rx
    cplx m00 = make_float2( cb*ca,  sb*sa);
    cplx m01 = make_float2(-sb*ca, -cb*sa);
    cplx m10 = make_float2( sb*ca, -cb*sa);
    cplx m11 = make_float2( cb*ca, -sb*sa);
    // U = Rz*M : row0 *= e^{-ic/2}, row1 *= e^{+ic/2}
    cplx e0 = make_float2(cc, -sc), e1 = make_float2(cc, sc);
    cplx u00 = cmul(e0, m00), u01 = cmul(e0, m01);
    cplx u10 = cmul(e1, m10), u11 = cmul(e1, m11);
    Ush[t][0] = u00; Ush[t][1] = u01; Ush[t][2] = u10; Ush[t][3] = u11;
    Ug[t*4+0] = u00; Ug[t*4+1] = u01; Ug[t*4+2] = u10; Ug[t*4+3] = u11;
  }
  __syncthreads();
  // layer-0 product state: amp(i) = prod_p U0[17-p][bit_p(i)][0]
  for (int m = t; m < 4096; m += blockDim.x) {
    cplx v = make_float2(1.f, 0.f);
    for (int p = 0; p < 12; ++p) {
      int q = 17 - p;
      cplx f = ((m >> p) & 1) ? Ush[q][2] : Ush[q][0];
      v = cmul(v, f);
    }
    prodLow[m] = v;
  }
  if (t < 64) {
    cplx v = make_float2(1.f, 0.f);
    for (int p = 12; p < 18; ++p) {
      int q = 17 - p;
      cplx f = ((t >> (p - 12)) & 1) ? Ush[q][2] : Ush[q][0];
      v = cmul(v, f);
    }
    prodHigh[t] = v;
  }
}

// --------------------------------------------------------------------------
// K_enc: h = relu(state@w1+b1); enc = h@w2+b2; xc = amp*exp(i*ph).
// 1024 blocks x 256 threads, 4 rows/block, 4 independent accumulators.
// --------------------------------------------------------------------------
__global__ __launch_bounds__(256) void k_enc(
    const float* __restrict__ state, const float* __restrict__ w1,
    const float* __restrict__ b1, const float* __restrict__ w2,
    const float* __restrict__ b2, float* __restrict__ xRe,
    float* __restrict__ xIm, float* __restrict__ xn2) {
  __shared__ float sState[4][256];
  __shared__ float hS[4][64];
  __shared__ float encS[4][36];
  __shared__ float wsum[4];
  int t = threadIdx.x;
  int r = t >> 6, j = t & 63;
  const float4* st4 =
      reinterpret_cast<const float4*>(state + (size_t)blockIdx.x * 1024);
  reinterpret_cast<float4*>(&sState[0][0])[t] = st4[t];
  __syncthreads();
  float a0 = 0.f, a1 = 0.f, a2 = 0.f, a3 = 0.f;
#pragma unroll 4
  for (int k = 0; k < 256; k += 4) {
    a0 = fmaf(sState[r][k+0], w1[(k+0)*64 + j], a0);
    a1 = fmaf(sState[r][k+1], w1[(k+1)*64 + j], a1);
    a2 = fmaf(sState[r][k+2], w1[(k+2)*64 + j], a2);
    a3 = fmaf(sState[r][k+3], w1[(k+3)*64 + j], a3);
  }
  hS[r][j] = fmaxf((a0 + a1) + (a2 + a3) + b1[j], 0.f);
  __syncthreads();
  if (j < 36) {
    float a = b2[j];
#pragma unroll 8
    for (int k = 0; k < 64; ++k) a = fmaf(hS[r][k], w2[k*36 + j], a);
    encS[r][j] = a;
  }
  __syncthreads();
  float lsum = 0.f;
  if (j < 18) {
    float amp = encS[r][j], ph = encS[r][18 + j];
    float sp, cp;
    sincosf(ph, &sp, &cp);
    int row = blockIdx.x*4 + r;
    xRe[row*18 + j] = amp * cp;
    xIm[row*18 + j] = amp * sp;
    lsum = amp * amp;
  }
  for (int off = 32; off > 0; off >>= 1) lsum += __shfl_down(lsum, off, 64);
  if (j == 0) wsum[r] = lsum;
  __syncthreads();
  if (t == 0) atomicAdd(xn2, wsum[0] + wsum[1] + wsum[2] + wsum[3]);
}

// --------------------------------------------------------------------------
// K_gatesLow: gates on bits 0..9 (qubits 17..8). 256 blocks x 512 thr,
// contiguous 1024-elem tiles in LDS. Input gathered through perm P.
// mode 0: layer-0 product state; mode 1: svIn[P(i)].
// --------------------------------------------------------------------------
__global__ __launch_bounds__(512) void k_gatesLow(
    const cplx* __restrict__ Ug, const cplx* __restrict__ prodLow,
    const cplx* __restrict__ prodHigh, const cplx* __restrict__ svIn,
    cplx* __restrict__ svOut, int layer, int mode) {
  __shared__ float sRe[1024], sIm[1024];
  int t = threadIdx.x;
  int base = blockIdx.x << 10;
  for (int e = t; e < 1024; e += 512) {
    int i = base + e;
    int src = (i ^ (i << 1)) & PMASK;   // CNOT-chain permutation
    cplx v;
    if (mode == 0) v = cmul(prodHigh[src >> 12], prodLow[src & 4095]);
    else           v = svIn[src];
    sRe[e] = v.x; sIm[e] = v.y;
  }
  __syncthreads();
  for (int p = 0; p < 10; ++p) {
    int q = 17 - p;
    const cplx* U = Ug + (layer*18 + q)*4;
    cplx u00 = U[0], u01 = U[1], u10 = U[2], u11 = U[3];
    {
      int k = t;
      int i0 = ((k >> p) << (p + 1)) | (k & ((1 << p) - 1));
      int i1 = i0 | (1 << p);
      cplx a = make_float2(sRe[i0], sIm[i0]);
      cplx b = make_float2(sRe[i1], sIm[i1]);
      cplx na = cadd(cmul(u00, a), cmul(u01, b));
      cplx nb = cadd(cmul(u10, a), cmul(u11, b));
      sRe[i0] = na.x; sIm[i0] = na.y;
      sRe[i1] = nb.x; sIm[i1] = nb.y;
    }
    __syncthreads();
  }
  for (int e = t; e < 1024; e += 512)
    svOut[base + e] = make_float2(sRe[e], sIm[e]);
}

// --------------------------------------------------------------------------
// K_gatesHigh: gates on bits 10..17 (qubits 7..0). 256 blocks x 512 thr.
// Tile = 256 h-values (bits 10..17) x 4 l-values; in-place (tiles partition
// by l-chunk). LDS index m = h*4 + j.
// --------------------------------------------------------------------------
__global__ __launch_bounds__(512) void k_gatesHigh(
    const cplx* __restrict__ Ug, cplx* __restrict__ sv, int layer) {
  __shared__ float tRe[1024], tIm[1024];
  int t = threadIdx.x;
  int l0 = blockIdx.x << 2;
  for (int e = t; e < 1024; e += 512) {
    int h = e >> 2, j = e & 3;
    cplx v = sv[h*1024 + l0 + j];
    tRe[e] = v.x; tIm[e] = v.y;
  }
  __syncthreads();
  for (int ph = 0; ph < 8; ++ph) {
    int q = 7 - ph;                    // bit p = 10+ph, qubit q = 17-p
    const cplx* U = Ug + (layer*18 + q)*4;
    cplx u00 = U[0], u01 = U[1], u10 = U[2], u11 = U[3];
    {
      int kh = t >> 2, j = t & 3;
      int h0 = ((kh >> ph) << (ph + 1)) | (kh & ((1 << ph) - 1));
      int h1 = h0 | (1 << ph);
      int i0 = h0*4 + j, i1 = h1*4 + j;
      cplx a = make_float2(tRe[i0], tIm[i0]);
      cplx b = make_float2(tRe[i1], tIm[i1]);
      cplx na = cadd(cmul(u00, a), cmul(u01, b));
      cplx nb = cadd(cmul(u10, a), cmul(u11, b));
      tRe[i0] = na.x; tIm[i0] = na.y;
      tRe[i1] = nb.x; tIm[i1] = nb.y;
    }
    __syncthreads();
  }
  for (int e = t; e < 1024; e += 512) {
    int h = e >> 2, j = e & 3;
    sv[h*1024 + l0 + j] = make_float2(tRe[e], tIm[e]);
  }
}

// --------------------------------------------------------------------------
// K_combine: final perm gather + add normalized x + build cl (re plane,
// im plane; unnormalized) + accumulate L2 = ||sv||^2.
// --------------------------------------------------------------------------
__global__ __launch_bounds__(256) void k_combine(
    const cplx* __restrict__ svIn, const float* __restrict__ xRe,
    const float* __restrict__ xIm, const float* __restrict__ xn2,
    float* __restrict__ cl, float* __restrict__ L2acc) {
  int t = threadIdx.x;
  float xs = xn2[0];
  float invXn = (xs > 0.f) ? (1.0f / sqrtf(xs)) : 1.0f;
  float lsum = 0.f;
  for (int u = 0; u < 4; ++u) {
    int i = blockIdx.x*1024 + u*256 + t;
    int src = (i ^ (i << 1)) & PMASK;
    cplx v = svIn[src];
    if (i < XLEN) {
      v.x = fmaf(xRe[i], invXn, v.x);
      v.y = fmaf(xIm[i], invXn, v.y);
    }
    cl[i] = v.x;
    cl[DIMSZ + i] = v.y;
    lsum += v.x*v.x + v.y*v.y;
  }
  for (int off = 32; off > 0; off >>= 1) lsum += __shfl_down(lsum, off, 64);
  if ((t & 63) == 0) atomicAdd(L2acc, lsum);
}

// --------------------------------------------------------------------------
// K_matvec: partial[slot][mat*64+c] += sum_r cl[r]*W[r,c] over a 512-row
// chunk. 2048 blocks (1024 chunks x 2 mats). Eight NAMED float4 loads per
// group -> 8 global_load_dwordx4 in flight per wave (8 KB); at ~28 waves/CU
// that is ~220 KB in flight per CU, far above the ~9 KB latency-BW product
// -> HBM-bound. No launch_bounds occupancy floor: let VGPR land ~56-64.
// --------------------------------------------------------------------------
__global__ __launch_bounds__(256) void k_matvec(
    const float* __restrict__ cl, const float* __restrict__ Wdec,
    const float* __restrict__ Wval, float* __restrict__ dots_rep) {
  __shared__ float clS[512];
  __shared__ float red[1024];
  int t = threadIdx.x;
  int mat = blockIdx.x & 1;
  int chunk = blockIdx.x >> 1;             // 0..1023
  size_t r0 = (size_t)chunk * 512;
  if (t < 128)
    reinterpret_cast<float4*>(clS)[t] =
        reinterpret_cast<const float4*>(cl + r0)[t];
  __syncthreads();
  const float* Wb = (mat ? Wval : Wdec) + r0*64 + (size_t)((t & 15)*4);
  int ro = t >> 4;
  float ax = 0.f, ay = 0.f, az = 0.f, aw = 0.f;
#pragma unroll
  for (int g = 0; g < 4; ++g) {
    int rr = g*128 + ro;
    const size_t rb = (size_t)rr * 64;
    // 8 independent named loads -> compiler emits 8 back-to-back
    // global_load_dwordx4 with descending vmcnt before the FMAs.
    float4 w0 = *reinterpret_cast<const float4*>(Wb + rb +   0*64);
    float4 w1 = *reinterpret_cast<const float4*>(Wb + rb +  16*64);
    float4 w2 = *reinterpret_cast<const float4*>(Wb + rb +  32*64);
    float4 w3 = *reinterpret_cast<const float4*>(Wb + rb +  48*64);
    float4 w4 = *reinterpret_cast<const float4*>(Wb + rb +  64*64);
    float4 w5 = *reinterpret_cast<const float4*>(Wb + rb +  80*64);
    float4 w6 = *reinterpret_cast<const float4*>(Wb + rb +  96*64);
    float4 w7 = *reinterpret_cast<const float4*>(Wb + rb + 112*64);
    float s0 = clS[rr+  0], s1 = clS[rr+ 16], s2 = clS[rr+ 32], s3 = clS[rr+ 48];
    float s4 = clS[rr+ 64], s5 = clS[rr+ 80], s6 = clS[rr+ 96], s7 = clS[rr+112];
    ax = fmaf(s0, w0.x, ax); ay = fmaf(s0, w0.y, ay); az = fmaf(s0, w0.z, az); aw = fmaf(s0, w0.w, aw);
    ax = fmaf(s1, w1.x, ax); ay = fmaf(s1, w1.y, ay); az = fmaf(s1, w1.z, az); aw = fmaf(s1, w1.w, aw);
    ax = fmaf(s2, w2.x, ax); ay = fmaf(s2, w2.y, ay); az = fmaf(s2, w2.z, az); aw = fmaf(s2, w2.w, aw);
    ax = fmaf(s3, w3.x, ax); ay = fmaf(s3, w3.y, ay); az = fmaf(s3, w3.z, az); aw = fmaf(s3, w3.w, aw);
    ax = fmaf(s4, w4.x, ax); ay = fmaf(s4, w4.y, ay); az = fmaf(s4, w4.z, az); aw = fmaf(s4, w4.w, aw);
    ax = fmaf(s5, w5.x, ax); ay = fmaf(s5, w5.y, ay); az = fmaf(s5, w5.z, az); aw = fmaf(s5, w5.w, aw);
    ax = fmaf(s6, w6.x, ax); ay = fmaf(s6, w6.y, ay); az = fmaf(s6, w6.z, az); aw = fmaf(s6, w6.w, aw);
    ax = fmaf(s7, w7.x, ax); ay = fmaf(s7, w7.y, ay); az = fmaf(s7, w7.z, az); aw = fmaf(s7, w7.w, aw);
  }
  red[t*4+0] = ax; red[t*4+1] = ay; red[t*4+2] = az; red[t*4+3] = aw;
  __syncthreads();
  if (t < 64) {
    int ci0 = t >> 2, jj = t & 3;
    float sum = 0.f;
#pragma unroll
    for (int r2 = 0; r2 < 16; ++r2) sum += red[(r2*16 + ci0)*4 + jj];
    int slot = chunk & 31;
    atomicAdd(&dots_rep[slot*128 + mat*64 + t], sum);
  }
}

// --------------------------------------------------------------------------
// K_final: sum 32 slots, apply invL, hidden relu + tiny second layers.
// --------------------------------------------------------------------------
__global__ void k_final(const float* __restrict__ dots_rep,
                        const float* __restrict__ L2acc,
                        const float* __restrict__ db1,
                        const float* __restrict__ dw2,
                        const float* __restrict__ db2,
                        const float* __restrict__ vb1,
                        const float* __restrict__ vw2,
                        const float* __restrict__ vb2,
                        float* __restrict__ out) {
  __shared__ float hd[64], hv[64];
  int t = threadIdx.x;
  float sd = 0.f, sva = 0.f;
#pragma unroll
  for (int s = 0; s < 32; ++s) {
    sd  += dots_rep[s*128 + t];
    sva += dots_rep[s*128 + 64 + t];
  }
  float invL = 1.0f / sqrtf(L2acc[0]);
  hd[t] = fmaxf(sd * invL + db1[t], 0.f);
  hv[t] = fmaxf(sva * invL + vb1[t], 0.f);
  __syncthreads();
  if (t < 18) {
    float s = db2[t];
    for (int k = 0; k < 64; ++k) s = fmaf(hd[k], dw2[k*18 + t], s);
    out[t] = s;
  }
  if (t == 20) {
    float s = vb2[0];
    for (int k = 0; k < 64; ++k) s = fmaf(hv[k], vw2[k], s);
    out[18] = s;
  }
}

extern "C" void kernel_launch(void* const* d_in, const int* in_sizes, int n_in,
                              void* d_out, int out_size, void* d_ws,
                              size_t ws_size, hipStream_t stream) {
  const float* state  = (const float*)d_in[0];
  const float* enc_w1 = (const float*)d_in[1];
  const float* enc_b1 = (const float*)d_in[2];
  const float* enc_w2 = (const float*)d_in[3];
  const float* enc_b2 = (const float*)d_in[4];
  const float* qparams= (const float*)d_in[5];
  const float* dec_w1 = (const float*)d_in[6];
  const float* dec_b1 = (const float*)d_in[7];
  const float* dec_w2 = (const float*)d_in[8];
  const float* dec_b2 = (const float*)d_in[9];
  const float* val_w1 = (const float*)d_in[10];
  const float* val_b1 = (const float*)d_in[11];
  const float* val_w2 = (const float*)d_in[12];
  const float* val_b2 = (const float*)d_in[13];

  float* wsf = (float*)d_ws;
  // ws layout (floats):
  float* dots_rep = wsf;                         // 32*128 = 4096
  float* xn2      = wsf + 4096;                  // 1
  float* L2acc    = wsf + 4097;                  // 1
  cplx*  Ug       = (cplx*)(wsf + 4352);         // 216 cplx (432 f)
  cplx*  prodLow  = (cplx*)(wsf + 8192);         // 4096 cplx (8192 f)
  cplx*  prodHigh = (cplx*)(wsf + 16384);        // 64 cplx (128 f)
  float* xRe      = wsf + 16640;                 // 73728
  float* xIm      = wsf + 90368;                 // 73728
  cplx*  svA      = (cplx*)(wsf + 164096);       // 262144 cplx
  cplx*  svB      = (cplx*)(wsf + 688384);       // 262144 cplx
  float* cl       = wsf + 1212672;               // 524288  (ends 1736960)

  hipLaunchKernelGGL(k_prep, dim3(1), dim3(256), 0, stream,
                     qparams, Ug, prodLow, prodHigh, wsf);
  hipLaunchKernelGGL(k_enc, dim3(1024), dim3(256), 0, stream,
                     state, enc_w1, enc_b1, enc_w2, enc_b2, xRe, xIm, xn2);
  // layer index 1: input = permuted layer-0 product state
  hipLaunchKernelGGL(k_gatesLow, dim3(256), dim3(512), 0, stream,
                     Ug, prodLow, prodHigh, (const cplx*)nullptr, svA, 1, 0);
  hipLaunchKernelGGL(k_gatesHigh, dim3(256), dim3(512), 0, stream, Ug, svA, 1);
  // layer index 2: input = svA gathered through perm P
  hipLaunchKernelGGL(k_gatesLow, dim3(256), dim3(512), 0, stream,
                     Ug, prodLow, prodHigh, (const cplx*)svA, svB, 2, 1);
  hipLaunchKernelGGL(k_gatesHigh, dim3(256), dim3(512), 0, stream, Ug, svB, 2);
  hipLaunchKernelGGL(k_combine, dim3(256), dim3(256), 0, stream,
                     svB, xRe, xIm, xn2, cl, L2acc);
  hipLaunchKernelGGL(k_matvec, dim3(2048), dim3(256), 0, stream,
                     cl, dec_w1, val_w1, dots_rep);
  hipLaunchKernelGGL(k_final, dim3(1), dim3(64), 0, stream,
                     dots_rep, L2acc, dec_b1, dec_w2, dec_b2,
                     val_b1, val_w2, val_b2, (float*)d_out);
}